// Round 1
// baseline (971.848 us; speedup 1.0000x reference)
//
#include <hip/hip_runtime.h>
#include <math.h>

#define NEURONS 64
#define HID 32
#define GD 103
#define CAP 1024   // max segment length kept in LDS (expected max ~316 for N/B=244)

// ---------------------------------------------------------------------------
// k_prep — two disjoint block ranges in one launch:
//   blocks [0, gp_blocks):           gpart[b][h] = b1[h] + sum_d gf[b][d]*W1[64+d][h]
//   blocks [gp_blocks, +bd_blocks):  start[b] = lower_bound(nb, b); start[B] = N
// ---------------------------------------------------------------------------
__global__ __launch_bounds__(256) void k_prep(
    const float* __restrict__ gf, const float* __restrict__ W1,
    const float* __restrict__ b1, const int* __restrict__ nb,
    float* __restrict__ gpart, int* __restrict__ start,
    int n, int B, int gp_blocks)
{
    if ((int)blockIdx.x < gp_blocks) {
        int t = blockIdx.x * 256 + threadIdx.x;
        if (t >= B * HID) return;
        int b = t >> 5;
        int h = t & 31;
        float acc = b1[h];
        const float* grow = gf + (size_t)b * GD;
        #pragma unroll
        for (int d = 0; d < GD; ++d)
            acc = fmaf(grow[d], W1[(NEURONS + d) * HID + h], acc);
        gpart[t] = acc;
    } else {
        int b = (blockIdx.x - gp_blocks) * 256 + threadIdx.x;
        if (b > B) return;
        if (b == B) { start[B] = n; return; }
        int lo = 0, hi = n;
        while (lo < hi) {
            int mid = (lo + hi) >> 1;
            if (nb[mid] < b) lo = mid + 1; else hi = mid;
        }
        start[b] = lo;
    }
}

// ---------------------------------------------------------------------------
__device__ __forceinline__ float wave_max(float v) {
    #pragma unroll
    for (int o = 32; o > 0; o >>= 1) v = fmaxf(v, __shfl_down(v, o, 64));
    return v;
}
__device__ __forceinline__ float wave_sum(float v) {
    #pragma unroll
    for (int o = 32; o > 0; o >>= 1) v += __shfl_down(v, o, 64);
    return v;
}

// ---------------------------------------------------------------------------
// k_fused — one block per graph (segment). Rows of a segment are contiguous.
//  * seg id = blockIdx.x -> no node_batch gather at all
//  * gpart row / W2 / b2 are block-uniform -> scalar (SGPR) operands
//  * each thread computes one row's GEMV from its own float4 loads (x read
//    exactly once; each float4 is consumed immediately -> no re-read fission)
//  * logits stay in LDS; block softmax; coalesced out write
//  * fallback to global workspace if a segment exceeds CAP (never in bench)
// ---------------------------------------------------------------------------
__global__ __launch_bounds__(256) void k_fused(
    const float* __restrict__ x, const float* __restrict__ gpart,
    const float* __restrict__ W1, const float* __restrict__ W2,
    const float* __restrict__ b2, const int* __restrict__ start,
    float* __restrict__ out, float* __restrict__ lg_ws)
{
    __shared__ float slog[CAP];
    __shared__ float sred[4];

    const int b = blockIdx.x;
    const int s = start[b];
    const int e = start[b + 1];
    const int len = e - s;
    if (len <= 0) return;                       // block-uniform
    const int tid = threadIdx.x;
    const int wid = tid >> 6;

    // block-uniform parameters: compiler emits scalar loads -> SGPRs
    float binit[HID], w2r[HID];
    const float* gp = gpart + (size_t)b * HID;
    #pragma unroll
    for (int h = 0; h < HID; ++h) binit[h] = gp[h];
    #pragma unroll
    for (int h = 0; h < HID; ++h) w2r[h] = W2[h];
    const float b2v = b2[0];

    const bool fits = (len <= CAP);             // block-uniform

    for (int i = s + tid; i < e; i += 256) {
        const float4* __restrict__ xr = (const float4*)(x + (size_t)i * NEURONS);
        float acc[HID];
        #pragma unroll
        for (int h = 0; h < HID; ++h) acc[h] = binit[h];
        #pragma unroll
        for (int q = 0; q < NEURONS / 4; ++q) {
            const float4 v = xr[q];
            const float* __restrict__ w = W1 + q * 4 * HID;
            #pragma unroll
            for (int h = 0; h < HID; ++h) acc[h] = fmaf(v.x, w[h],           acc[h]);
            #pragma unroll
            for (int h = 0; h < HID; ++h) acc[h] = fmaf(v.y, w[HID + h],     acc[h]);
            #pragma unroll
            for (int h = 0; h < HID; ++h) acc[h] = fmaf(v.z, w[2 * HID + h], acc[h]);
            #pragma unroll
            for (int h = 0; h < HID; ++h) acc[h] = fmaf(v.w, w[3 * HID + h], acc[h]);
        }
        float logit = b2v;
        #pragma unroll
        for (int h = 0; h < HID; ++h) {
            float z = acc[h];
            float sp = fmaxf(z, 0.0f) + __logf(1.0f + __expf(-fabsf(z)));
            logit = fmaf(sp, w2r[h], logit);
        }
        if (fits) slog[i - s] = logit;
        else      lg_ws[i] = logit;
    }
    __syncthreads();

    if (fits) {
        float m = -INFINITY;
        for (int j = tid; j < len; j += 256) m = fmaxf(m, slog[j]);
        m = wave_max(m);
        if ((tid & 63) == 0) sred[wid] = m;
        __syncthreads();
        const float bm = fmaxf(fmaxf(sred[0], sred[1]), fmaxf(sred[2], sred[3]));
        __syncthreads();

        float sum = 0.0f;
        for (int j = tid; j < len; j += 256) sum += __expf(slog[j] - bm);
        sum = wave_sum(sum);
        if ((tid & 63) == 0) sred[wid] = sum;
        __syncthreads();
        const float inv = 1.0f / (sred[0] + sred[1] + sred[2] + sred[3]);

        for (int j = tid; j < len; j += 256)
            out[s + j] = __expf(slog[j] - bm) * inv;
    } else {
        const float* lg = lg_ws + s;
        float m = -INFINITY;
        for (int j = tid; j < len; j += 256) m = fmaxf(m, lg[j]);
        m = wave_max(m);
        if ((tid & 63) == 0) sred[wid] = m;
        __syncthreads();
        const float bm = fmaxf(fmaxf(sred[0], sred[1]), fmaxf(sred[2], sred[3]));
        __syncthreads();

        float sum = 0.0f;
        for (int j = tid; j < len; j += 256) sum += __expf(lg[j] - bm);
        sum = wave_sum(sum);
        if ((tid & 63) == 0) sred[wid] = sum;
        __syncthreads();
        const float inv = 1.0f / (sred[0] + sred[1] + sred[2] + sred[3]);

        for (int j = tid; j < len; j += 256)
            out[s + j] = __expf(lg[j] - bm) * inv;
    }
}

// ---------------------------------------------------------------------------
extern "C" void kernel_launch(void* const* d_in, const int* in_sizes, int n_in,
                              void* d_out, int out_size, void* d_ws, size_t ws_size,
                              hipStream_t stream)
{
    const float* x  = (const float*)d_in[0];
    const int*   nb = (const int*)d_in[1];
    const float* gf = (const float*)d_in[2];
    const float* W1 = (const float*)d_in[3];
    const float* b1 = (const float*)d_in[4];
    const float* W2 = (const float*)d_in[5];
    const float* b2 = (const float*)d_in[6];
    float* out = (float*)d_out;

    const int N = in_sizes[1];
    const int B = in_sizes[2] / GD;

    float* gpart = (float*)d_ws;                       // B*HID floats
    int*   start = (int*)(gpart + (size_t)B * HID);    // B+1 ints
    float* lg_ws = (float*)(start + (B + 2));          // N floats (fallback only)

    const int gp_blocks = (B * HID + 255) / 256;
    const int bd_blocks = (B + 1 + 255) / 256;
    k_prep<<<gp_blocks + bd_blocks, 256, 0, stream>>>(gf, W1, b1, nb, gpart, start,
                                                      N, B, gp_blocks);
    k_fused<<<B, 256, 0, stream>>>(x, gpart, W1, W2, b2, start, out, lg_ws);
}

// Round 2
// 758.811 us; speedup vs baseline: 1.2808x; 1.2808x over previous
//
#include <hip/hip_runtime.h>
#include <math.h>

#define NEURONS 64
#define HID 32
#define GD 103
#define TW 16                 // columns per chunk
#define NCHUNK (NEURONS / TW)
#define ROWS 256              // rows per block
#define CAP 1024              // k_seg LDS capacity (max expected segment ~320)

// ---------------------------------------------------------------------------
// k_prep — two disjoint block ranges in one launch:
//   blocks [0, gp_blocks):           gpart[b][h] = b1[h] + sum_d gf[b][d]*W1[64+d][h]
//   blocks [gp_blocks, +bd_blocks):  start[b] = lower_bound(nb, b); start[B] = N
// ---------------------------------------------------------------------------
__global__ __launch_bounds__(256) void k_prep(
    const float* __restrict__ gf, const float* __restrict__ W1,
    const float* __restrict__ b1, const int* __restrict__ nb,
    float* __restrict__ gpart, int* __restrict__ start,
    int n, int B, int gp_blocks)
{
    if ((int)blockIdx.x < gp_blocks) {
        int t = blockIdx.x * 256 + threadIdx.x;
        if (t >= B * HID) return;
        int b = t >> 5;
        int h = t & 31;
        float acc = b1[h];
        const float* grow = gf + (size_t)b * GD;
        #pragma unroll
        for (int d = 0; d < GD; ++d)
            acc = fmaf(grow[d], W1[(NEURONS + d) * HID + h], acc);
        gpart[t] = acc;
    } else {
        int b = (blockIdx.x - gp_blocks) * 256 + threadIdx.x;
        if (b > B) return;
        if (b == B) { start[B] = n; return; }
        int lo = 0, hi = n;
        while (lo < hi) {
            int mid = (lo + hi) >> 1;
            if (nb[mid] < b) lo = mid + 1; else hi = mid;
        }
        start[b] = lo;
    }
}

// ---------------------------------------------------------------------------
// k_logits — LDS-staged streaming GEMV with async global->LDS DMA.
//  * staging: __builtin_amdgcn_global_load_lds, 16 B/lane, 1 KiB/wave-instr.
//    LDS dest is linear (DMA requirement); bank behavior recovered by
//    PRE-SWIZZLING THE GLOBAL SOURCE: LDS slot (row, j) holds x quarter
//    j ^ ((row>>1)&3). Compute reads ds_read_b128 at j = q ^ ((tid>>1)&3):
//    8-way conflict floor (~3x on LDS pipe), hidden under 1024 cyc of FMA.
//  * pipeline: stage(c+1) issued BEFORE compute(c); the barrier after
//    compute drains vmcnt -> next chunk's flight overlaps this chunk's FMAs.
//  * weights W1 are wave-uniform -> scalar (SGPR) operands, 1 SGPR per FMA.
// ---------------------------------------------------------------------------
__global__ __launch_bounds__(256) void k_logits(
    const float* __restrict__ x, const int* __restrict__ nb,
    const float* __restrict__ gpart, const float* __restrict__ W1,
    const float* __restrict__ W2, const float* __restrict__ b2,
    float* __restrict__ logits, int n)
{
    __shared__ float xs[2][ROWS * TW];   // 2 x 16 KiB

    const int tid = threadIdx.x;
    const long base = (long)blockIdx.x * ROWS;
    const long i = base + tid;
    const bool alive = i < (long)n;
    const long ic = alive ? i : (long)(n - 1);

#define STAGE(c, buf) do {                                                   \
        _Pragma("unroll")                                                    \
        for (int k = 0; k < 4; ++k) {                                        \
            int p = tid + 256 * k;                                           \
            int row = p >> 2, jq = p & 3;                                    \
            int qs = jq ^ ((row >> 1) & 3);                                  \
            long r = base + row; if (r >= (long)n) r = (long)n - 1;          \
            const float* srcp = x + r * NEURONS + (c) * TW + qs * 4;         \
            __builtin_amdgcn_global_load_lds(                                \
                (const __attribute__((address_space(1))) void*)srcp,         \
                (__attribute__((address_space(3))) void*)(&xs[(buf)][p * 4]),\
                16, 0, 0);                                                   \
        }                                                                    \
    } while (0)

    // kick off chunk 0 DMA immediately; its flight covers the gpart gather
    STAGE(0, 0);

    const int seg = nb[ic];
    float acc[HID];
    const float4* gp = (const float4*)(gpart + (size_t)seg * HID);
    #pragma unroll
    for (int q = 0; q < HID / 4; ++q) {
        float4 v = gp[q];
        acc[4 * q + 0] = v.x; acc[4 * q + 1] = v.y;
        acc[4 * q + 2] = v.z; acc[4 * q + 3] = v.w;
    }

    __syncthreads();   // drains vmcnt(0): chunk 0 landed

    const int jx = (tid >> 1) & 3;     // per-thread read swizzle
    #pragma unroll
    for (int c = 0; c < NCHUNK; ++c) {
        if (c + 1 < NCHUNK) STAGE(c + 1, (c + 1) & 1);   // async, other buffer

        const char* bufc = (const char*)&xs[c & 1][0];
        #pragma unroll
        for (int q = 0; q < 4; ++q) {
            const int j = q ^ jx;
            const float4 xv = *(const float4*)(bufc + tid * 64 + j * 16);
            const float* w = W1 + (c * TW + q * 4) * HID;
            #pragma unroll
            for (int h = 0; h < HID; ++h) acc[h] = fmaf(xv.x, w[h],           acc[h]);
            #pragma unroll
            for (int h = 0; h < HID; ++h) acc[h] = fmaf(xv.y, w[HID + h],     acc[h]);
            #pragma unroll
            for (int h = 0; h < HID; ++h) acc[h] = fmaf(xv.z, w[2 * HID + h], acc[h]);
            #pragma unroll
            for (int h = 0; h < HID; ++h) acc[h] = fmaf(xv.w, w[3 * HID + h], acc[h]);
        }
        __syncthreads();   // drains stage(c+1) flight + all ds reads of buf c
    }
#undef STAGE

    if (!alive) return;

    float logit = b2[0];
    #pragma unroll
    for (int h = 0; h < HID; ++h) {
        float z = acc[h];
        float sp = fmaxf(z, 0.0f) + __logf(1.0f + __expf(-fabsf(z)));
        logit = fmaf(sp, W2[h], logit);
    }
    logits[i] = logit;
}

// ---------------------------------------------------------------------------
// k_seg — one block per segment. Stage logits into LDS once, then
// max / sum(exp) / normalize passes run LDS-resident (one global read,
// one global write per element). Global fallback for oversized segments.
// ---------------------------------------------------------------------------
__device__ __forceinline__ float wave_max(float v) {
    #pragma unroll
    for (int o = 32; o > 0; o >>= 1) v = fmaxf(v, __shfl_down(v, o, 64));
    return v;
}
__device__ __forceinline__ float wave_sum(float v) {
    #pragma unroll
    for (int o = 32; o > 0; o >>= 1) v += __shfl_down(v, o, 64);
    return v;
}

__global__ __launch_bounds__(256) void k_seg(
    const float* __restrict__ logits, const int* __restrict__ start,
    float* __restrict__ out)
{
    __shared__ float slog[CAP];
    __shared__ float sred[4];

    const int b = blockIdx.x;
    const int s = start[b], e = start[b + 1];
    const int len = e - s;
    if (len <= 0) return;                  // block-uniform
    const int tid = threadIdx.x;
    const int wid = tid >> 6;
    const bool fits = (len <= CAP);        // block-uniform

    if (fits) {
        for (int j = tid; j < len; j += 256) slog[j] = logits[s + j];
        __syncthreads();

        float m = -INFINITY;
        for (int j = tid; j < len; j += 256) m = fmaxf(m, slog[j]);
        m = wave_max(m);
        if ((tid & 63) == 0) sred[wid] = m;
        __syncthreads();
        const float bm = fmaxf(fmaxf(sred[0], sred[1]), fmaxf(sred[2], sred[3]));
        __syncthreads();

        float sum = 0.0f;
        for (int j = tid; j < len; j += 256) sum += __expf(slog[j] - bm);
        sum = wave_sum(sum);
        if ((tid & 63) == 0) sred[wid] = sum;
        __syncthreads();
        const float inv = 1.0f / (sred[0] + sred[1] + sred[2] + sred[3]);

        for (int j = tid; j < len; j += 256)
            out[s + j] = __expf(slog[j] - bm) * inv;
    } else {
        float m = -INFINITY;
        for (int j = s + tid; j < e; j += 256) m = fmaxf(m, logits[j]);
        m = wave_max(m);
        if ((tid & 63) == 0) sred[wid] = m;
        __syncthreads();
        const float bm = fmaxf(fmaxf(sred[0], sred[1]), fmaxf(sred[2], sred[3]));
        __syncthreads();

        float sum = 0.0f;
        for (int j = s + tid; j < e; j += 256) sum += __expf(logits[j] - bm);
        sum = wave_sum(sum);
        if ((tid & 63) == 0) sred[wid] = sum;
        __syncthreads();
        const float inv = 1.0f / (sred[0] + sred[1] + sred[2] + sred[3]);

        for (int j = s + tid; j < e; j += 256)
            out[j] = __expf(logits[j] - bm) * inv;
    }
}

// ---------------------------------------------------------------------------
extern "C" void kernel_launch(void* const* d_in, const int* in_sizes, int n_in,
                              void* d_out, int out_size, void* d_ws, size_t ws_size,
                              hipStream_t stream)
{
    const float* x  = (const float*)d_in[0];
    const int*   nb = (const int*)d_in[1];
    const float* gf = (const float*)d_in[2];
    const float* W1 = (const float*)d_in[3];
    const float* b1 = (const float*)d_in[4];
    const float* W2 = (const float*)d_in[5];
    const float* b2 = (const float*)d_in[6];
    float* out = (float*)d_out;

    const int N = in_sizes[1];
    const int B = in_sizes[2] / GD;

    float* gpart  = (float*)d_ws;                      // B*HID floats
    int*   start  = (int*)(gpart + (size_t)B * HID);   // B+1 ints
    float* logits = (float*)(start + (B + 2));         // N floats

    const int gp_blocks = (B * HID + 255) / 256;
    const int bd_blocks = (B + 1 + 255) / 256;
    k_prep<<<gp_blocks + bd_blocks, 256, 0, stream>>>(gf, W1, b1, nb, gpart, start,
                                                      N, B, gp_blocks);

    const int n_blocks = (N + ROWS - 1) / ROWS;
    k_logits<<<n_blocks, 256, 0, stream>>>(x, nb, gpart, W1, W2, b2, logits, N);

    k_seg<<<B, 256, 0, stream>>>(logits, start, out);
}